// Round 10
// baseline (288.894 us; speedup 1.0000x reference)
//
#include <hip/hip_runtime.h>
#include <math.h>

#define Fdim 128
#define Pw   16
#define Hh   8
#define Cc   32
#define Bb   8

typedef short  short8  __attribute__((ext_vector_type(8)));
typedef float  floatx4 __attribute__((ext_vector_type(4)));

#define QSCL   0.2550348637f      /* (1/sqrt(32)) * log2(e) */
#define MASKC2 (-144.26950408889634f)  /* -100 * log2(e) */

__device__ __forceinline__ float gelu_f(float x){
    return 0.5f * x * (1.0f + erff(x * 0.70710678118654752f));
}
// pack two fp32 -> bf16x2 (round-half-up) in 3 VALU ops via v_perm_b32
__device__ __forceinline__ unsigned pk2(float a, float b){
    unsigned ua = __builtin_bit_cast(unsigned, a) + 0x8000u;
    unsigned ub = __builtin_bit_cast(unsigned, b) + 0x8000u;
    return __builtin_amdgcn_perm(ub, ua, 0x07060302);
}
// truncating pack (1 op) — used for P in [0,1]; <=1ulp bf16 error
__device__ __forceinline__ unsigned pk2t(float a, float b){
    return __builtin_amdgcn_perm(__builtin_bit_cast(unsigned, b),
                                 __builtin_bit_cast(unsigned, a), 0x07060302);
}
__device__ __forceinline__ short bf16s(float a){
    return (short)((__builtin_bit_cast(unsigned, a) + 0x8000u) >> 16);
}
__device__ __forceinline__ float hi2f(unsigned d){ return __builtin_bit_cast(float, d & 0xffff0000u); }
__device__ __forceinline__ float lo2f(unsigned d){ return __builtin_bit_cast(float, d << 16); }

// ---------------- prep: bf16 weight repacks + V*Wrev fusion ----------------
__global__ __launch_bounds__(256) void prep_kernel(
    const float* __restrict__ qkv_w, const float* __restrict__ rev_w,
    const float* __restrict__ rpbt,  const float* __restrict__ lp1_w,
    const float* __restrict__ conv_w, const float* __restrict__ lp2_w,
    const float* __restrict__ qkv_b, const float* __restrict__ rev_b,
    short* __restrict__ qkv_wT, short* __restrict__ rev_wT, unsigned* __restrict__ rplb,
    short* __restrict__ lp1_wT, short* __restrict__ conv_wT, short* __restrict__ lp2_wT,
    short* __restrict__ wvr, float* __restrict__ rbtot)
{
    int i = blockIdx.x * 256 + threadIdx.x;
    if (i < 24576){
        int col = i >> 5, c = i & 31;
        qkv_wT[i] = bf16s(qkv_w[c*768 + col]);
    } else if (i < 32768){
        int j = i - 24576;
        int h = j >> 10, r = j & 1023;
        int c = r >> 5, a = r & 31;
        rev_wT[j] = bf16s(rev_w[(h*32 + a)*32 + c]);
    } else if (i < 40464){
        int j = i - 32768;
        int h = j / 962, d = j % 962;
        int g0 = (d < 481) ? (2*d) : (2*(d-481) + 1);
        float f0 = (g0     < 961) ? rpbt[g0*8 + h]*1.4426950408889634f : 0.f;
        float f1 = (g0 + 1 < 961) ? rpbt[(g0+1)*8 + h]*1.4426950408889634f : 0.f;
        rplb[j] = pk2(f0, f1);
    } else if (i < 44560){
        int j = i - 40464;
        int f = j >> 5, c = j & 31;
        lp1_wT[j] = bf16s(lp1_w[c*128 + f]);
    } else if (i < 192016){
        int j = i - 44560;                 // [kc][tap][kchunk][co][8]
        int ci_in = j & 7;
        int co    = (j >> 3) & 127;
        int chk   = (j >> 10) & 3;
        int s     = j >> 12;               // 0..35
        int tap = s % 9, kc = s / 9;
        conv_wT[j] = bf16s(conv_w[(tap*128 + kc*32 + chk*8 + ci_in)*128 + co]);
    } else if (i < 196112){
        int j = i - 192016;
        int oc = j >> 7, co = j & 127;
        lp2_wT[j] = bf16s(lp2_w[co*32 + oc]);
    } else if (i < 204304){
        int j  = i - 196112;               // [h][cout][c]
        int h  = j >> 10, aa = (j >> 5) & 31, c = j & 31;
        float s = 0.f;
        for (int a = 0; a < 32; a++)
            s += qkv_w[c*768 + 512 + h*32 + a] * rev_w[(h*32 + a)*32 + aa];
        wvr[j] = bf16s(s);
    } else if (i < 204336){
        int aa = i - 204304;
        float s = rev_b[aa];
        for (int m = 0; m < 256; m++)
            s += qkv_b[512 + m] * rev_w[m*32 + aa];
        rbtot[aa] = s;
    }
}

// ---------------- MFMA shifted-window attention, 512 threads (8 waves) ----------------
__global__
__attribute__((amdgpu_flat_work_group_size(512,512), amdgpu_waves_per_eu(4,4)))
void attn_kernel(
    const float* __restrict__ x,   const float* __restrict__ n1g,
    const float* __restrict__ n1b, const float* __restrict__ mod_w,
    const float* __restrict__ qkv_b, const float* __restrict__ rbtot,
    const short* __restrict__ qkv_wT, const short* __restrict__ wvr,
    const unsigned* __restrict__ rplb,
    float* __restrict__ x_res)
{
    __shared__ __align__(16) short hmodS[4*256*8];  // [kchunk][tok][8]
    __shared__ __align__(16) short Kbuf[256*40];    // [tok][a]
    __shared__ __align__(16) short Qbuf[256*40];    // [tok][a] -> PT
    __shared__ __align__(16) short VTb[32*264];     // [c][tok]  (V~ = V@Wrev)
    __shared__ __align__(16) unsigned rplbS[962];
    __shared__ unsigned regnp[64];

    const int w  = blockIdx.x;
    const int b  = w >> 6;
    const int wi = w & 63;
    const int wh = wi >> 3, ww = wi & 7;
    const int tid  = threadIdx.x;
    const int wv   = tid >> 6;    // 0..7
    const int ln   = tid & 63;
    const int quad = ln >> 4;
    const int l15  = ln & 15;
    const bool masked = (wh == 7) || (ww == 7);

    // ---- stage: LN1 + mod_w -> hmodS bf16 (chunked layout); region table ----
    if (tid < 256){
        const int n  = tid;
        const int rn = n >> 4, cn = n & 15;
        const int gh = (wh*Pw + rn + 8) & 127;
        const int gw = (ww*Pw + cn + 8) & 127;
        const float* xr = x + (((size_t)b << 14) + (gh << 7) + gw) * Cc;
        float v[Cc];
        const float4* x4 = reinterpret_cast<const float4*>(xr);
        float4* v4 = reinterpret_cast<float4*>(v);
        #pragma unroll
        for (int i = 0; i < Cc/4; i++) v4[i] = x4[i];
        float mean = 0.f;
        #pragma unroll
        for (int c = 0; c < Cc; c++) mean += v[c];
        mean *= (1.0f/Cc);
        float var = 0.f;
        #pragma unroll
        for (int c = 0; c < Cc; c++){ float d = v[c] - mean; var = fmaf(d, d, var); }
        var *= (1.0f/Cc);
        const float rinv = rsqrtf(var + 1e-5f);
        #pragma unroll
        for (int c = 0; c < Cc; c++)
            v[c] = (v[c] - mean)*rinv*n1g[c] + n1b[c] + mod_w[n*Cc + c];
        #pragma unroll
        for (int i = 0; i < 4; i++){
            uint4 dw;
            dw.x = pk2(v[8*i+0], v[8*i+1]);
            dw.y = pk2(v[8*i+2], v[8*i+3]);
            dw.z = pk2(v[8*i+4], v[8*i+5]);
            dw.w = pk2(v[8*i+6], v[8*i+7]);
            *(uint4*)(&hmodS[i*2048 + n*8]) = dw;
        }
    }
    if (tid < 64){
        int rm  = tid >> 2;
        int shm = wh*Pw + rm;
        int hreg = (shm < 112) ? 0 : ((shm < 120) ? 1 : 2);
        unsigned dw = 0;
        #pragma unroll
        for (int i = 0; i < 4; i++){
            int cm  = (tid & 3)*4 + i;
            int swm = ww*Pw + cm;
            int wreg = (swm < 112) ? 0 : ((swm < 120) ? 1 : 2);
            dw |= (unsigned)(hreg*3 + wreg) << (8*i);
        }
        regnp[tid] = dw;
    }
    __syncthreads();

    unsigned regq[2] = {0,0};
    if (masked){
        #pragma unroll
        for (int nt = 0; nt < 2; nt++){
            int q = wv*32 + nt*16 + l15;
            regq[nt] = (regnp[q >> 2] >> ((q & 3)*8)) & 255u;
        }
    }

    floatx4 RV[2][2];
    #pragma unroll
    for (int cm = 0; cm < 2; cm++)
        #pragma unroll
        for (int nt = 0; nt < 2; nt++)
            RV[cm][nt] = (floatx4){0.f,0.f,0.f,0.f};

    const int s0lane = 12 + l15 - 4*quad;
    const floatx4 zz = (floatx4){0.f,0.f,0.f,0.f};
    const short8 ONEv = {0x3F80,0x3F80,0x3F80,0x3F80,0x3F80,0x3F80,0x3F80,0x3F80};

    for (int h = 0; h < Hh; h++){
        __syncthreads();   // B1: prev head's Kbuf/VTb/rplbS reads done

        #pragma unroll
        for (int k2 = 0; k2 < 2; k2++){
            int i = k2*512 + tid;
            if (i < 962) rplbS[i] = rplb[h*962 + i];
        }

        // ---- QKV phase (V is the fused V@Wrev) ----
        short8 HF[2];
        #pragma unroll
        for (int ii = 0; ii < 2; ii++)
            HF[ii] = *(const short8*)(&hmodS[quad*2048 + (wv*32 + ii*16 + l15)*8]);
        short8 WQ[2], WK[2], WVb[2];
        float4 bq[2], bk[2];
        #pragma unroll
        for (int mt = 0; mt < 2; mt++){
            WQ[mt]  = *(const short8*)(qkv_wT + (      h*32 + mt*16 + l15)*32 + quad*8);
            WK[mt]  = *(const short8*)(qkv_wT + (256 + h*32 + mt*16 + l15)*32 + quad*8);
            WVb[mt] = *(const short8*)(wvr    + (      h*32 + mt*16 + l15)*32 + quad*8);
            bq[mt]  = *(const float4*)(qkv_b +       h*32 + mt*16 + quad*4);
            bk[mt]  = *(const float4*)(qkv_b + 256 + h*32 + mt*16 + quad*4);
        }
        #pragma unroll
        for (int ii = 0; ii < 2; ii++){
            const int tok = wv*32 + ii*16;
            #pragma unroll
            for (int mt = 0; mt < 2; mt++){
                floatx4 qf = __builtin_amdgcn_mfma_f32_16x16x32_bf16(WQ[mt], HF[ii], zz, 0,0,0);
                floatx4 kf = __builtin_amdgcn_mfma_f32_16x16x32_bf16(WK[mt], HF[ii], zz, 0,0,0);
                floatx4 vf = __builtin_amdgcn_mfma_f32_16x16x32_bf16(HF[ii], WVb[mt], zz, 0,0,0);
                uint2 qv;
                qv.x = pk2((qf[0]+bq[mt].x)*QSCL, (qf[1]+bq[mt].y)*QSCL);
                qv.y = pk2((qf[2]+bq[mt].z)*QSCL, (qf[3]+bq[mt].w)*QSCL);
                *(uint2*)(&Qbuf[(tok + l15)*40 + mt*16 + quad*4]) = qv;
                uint2 kv;
                kv.x = pk2(kf[0]+bk[mt].x, kf[1]+bk[mt].y);
                kv.y = pk2(kf[2]+bk[mt].z, kf[3]+bk[mt].w);
                *(uint2*)(&Kbuf[(tok + l15)*40 + mt*16 + quad*4]) = kv;
                uint2 vv;
                vv.x = pk2(vf[0], vf[1]);
                vv.y = pk2(vf[2], vf[3]);
                *(uint2*)(&VTb[(mt*16 + l15)*264 + tok + quad*4]) = vv;
            }
        }
        __syncthreads();   // B2

        short8 QB[2];
        #pragma unroll
        for (int nt = 0; nt < 2; nt++)
            QB[nt] = *(const short8*)(&Qbuf[(wv*32 + nt*16 + l15)*40 + quad*8]);

        floatx4 OT[2][2];
        #pragma unroll
        for (int am = 0; am < 2; am++)
            #pragma unroll
            for (int nt = 0; nt < 2; nt++)
                OT[am][nt] = (floatx4){0.f,0.f,0.f,0.f};
        floatx4 RS[2] = {zz, zz};   // rowsum via ones-MFMA

        for (int ch = 0; ch < 8; ch++){
            short8 KA[2];
            KA[0] = *(const short8*)(&Kbuf[(ch*32 +      l15)*40 + quad*8]);
            KA[1] = *(const short8*)(&Kbuf[(ch*32 + 16 + l15)*40 + quad*8]);

            unsigned pd0[3], pd1[3];
            int base = wv*2 - ch*2;
            #pragma unroll
            for (int j = 0; j < 3; j++){
                int dt  = base + j - 1;
                int g0  = (dt + 15)*31 + s0lane;
                int dwi = (g0 & 1) ? (481 + (g0 >> 1)) : (g0 >> 1);
                pd0[j] = rplbS[dwi];
                pd1[j] = rplbS[dwi + 1];
            }
            unsigned rk[2] = {0,0};
            if (masked){
                rk[0] = regnp[ch*8 +     quad];
                rk[1] = regnp[ch*8 + 4 + quad];
            }

            #pragma unroll
            for (int sub = 0; sub < 2; sub++){
                #pragma unroll
                for (int nt = 0; nt < 2; nt++){
                    int j = nt - sub + 1;
                    floatx4 ci;
                    ci[0] = hi2f(pd1[j]); ci[1] = lo2f(pd1[j]);
                    ci[2] = hi2f(pd0[j]); ci[3] = lo2f(pd0[j]);
                    if (masked){
                        ci[0] += (((rk[sub]      ) & 255u) == regq[nt]) ? 0.f : MASKC2;
                        ci[1] += (((rk[sub] >>  8) & 255u) == regq[nt]) ? 0.f : MASKC2;
                        ci[2] += (((rk[sub] >> 16) & 255u) == regq[nt]) ? 0.f : MASKC2;
                        ci[3] += (((rk[sub] >> 24) & 255u) == regq[nt]) ? 0.f : MASKC2;
                    }
                    floatx4 S = __builtin_amdgcn_mfma_f32_16x16x32_bf16(KA[sub], QB[nt], ci, 0,0,0);
                    float p0 = __builtin_amdgcn_exp2f(S[0]);
                    float p1 = __builtin_amdgcn_exp2f(S[1]);
                    float p2 = __builtin_amdgcn_exp2f(S[2]);
                    float p3 = __builtin_amdgcn_exp2f(S[3]);
                    uint2 pv; pv.x = pk2t(p0, p1); pv.y = pk2t(p2, p3);
                    *(uint2*)(&Qbuf[(wv*32 + nt*16 + l15)*40 + sub*16 + quad*4]) = pv;
                }
            }

            short8 VA0 = *(const short8*)(&VTb[(     l15)*264 + ch*32 + quad*8]);
            short8 VA1 = *(const short8*)(&VTb[(16 + l15)*264 + ch*32 + quad*8]);
            #pragma unroll
            for (int nt = 0; nt < 2; nt++){
                short8 PB = *(const short8*)(&Qbuf[(wv*32 + nt*16 + l15)*40 + quad*8]);
                OT[0][nt] = __builtin_amdgcn_mfma_f32_16x16x32_bf16(VA0, PB, OT[0][nt], 0,0,0);
                OT[1][nt] = __builtin_amdgcn_mfma_f32_16x16x32_bf16(VA1, PB, OT[1][nt], 0,0,0);
                RS[nt]    = __builtin_amdgcn_mfma_f32_16x16x32_bf16(ONEv, PB, RS[nt], 0,0,0);
            }
        }

        // accumulate this head: RV += OT / rowsum  (fp32, no LDS roundtrip)
        float inv[2];
        inv[0] = 1.0f / RS[0][0];
        inv[1] = 1.0f / RS[1][0];
        #pragma unroll
        for (int am = 0; am < 2; am++)
            #pragma unroll
            for (int nt = 0; nt < 2; nt++){
                floatx4 o = OT[am][nt];
                float iv = inv[nt];
                RV[am][nt][0] = fmaf(o[0], iv, RV[am][nt][0]);
                RV[am][nt][1] = fmaf(o[1], iv, RV[am][nt][1]);
                RV[am][nt][2] = fmaf(o[2], iv, RV[am][nt][2]);
                RV[am][nt][3] = fmaf(o[3], iv, RV[am][nt][3]);
            }
    }

    // ---- epilogue: x_res = x + rbtot + attn_out ----
    #pragma unroll
    for (int cm = 0; cm < 2; cm++){
        float4 rb = *(const float4*)(rbtot + cm*16 + quad*4);
        #pragma unroll
        for (int nt = 0; nt < 2; nt++){
            int gh = (wh*Pw + wv*2 + nt + 8) & 127;
            int gw = (ww*Pw + l15 + 8) & 127;
            size_t gaddr = (((size_t)b << 14) + (gh << 7) + gw)*Cc + cm*16 + quad*4;
            float4 xv = *(const float4*)(x + gaddr);
            floatx4 o = RV[cm][nt];
            float4 ov;
            ov.x = xv.x + rb.x + o[0];
            ov.y = xv.y + rb.y + o[1];
            ov.z = xv.z + rb.z + o[2];
            ov.w = xv.w + rb.w + o[3];
            *(float4*)(x_res + gaddr) = ov;
        }
    }
}

// ---------------- LeFF via MFMA, 512 threads (8 waves) ----------------
// Weights staged in 3-tap (one-ky-row) groups: single-buffered 24 KB wbuf,
// next group register-prefetched after the barrier -> 2 barriers per 3 taps
// instead of 2 per tap (~26 vs ~74 barriers/block).
__global__
__attribute__((amdgpu_flat_work_group_size(512,512), amdgpu_waves_per_eu(4,4)))
void leff_kernel(
    const float* __restrict__ x_res, const float* __restrict__ n2g,
    const float* __restrict__ n2b,  const float* __restrict__ lp1_b,
    const float* __restrict__ conv_b, const float* __restrict__ lp2_b,
    const short* __restrict__ lp1_wT, const short* __restrict__ conv_wT,
    const short* __restrict__ lp2_wT, float* __restrict__ out)
{
    __shared__ __align__(16) char lds[78336];
    short* xa   = (short*)lds;             // [336][40] bf16 LN2(halo)
    short* y1c  = (short*)(lds + 26880);   // [336][40] bf16 y1 chunk
    short* wbuf = (short*)(lds + 53760);   // [3][kchunk4][co128][8] single buffer
    short* y2   = (short*)lds;             // [256][136] overlay after conv

    const int blk = blockIdx.x;
    const int b   = blk >> 6;
    const int ty  = (blk >> 3) & 7, tx = blk & 7;
    const int tid  = threadIdx.x;
    const int wv   = tid >> 6;    // 0..7
    const int ln   = tid & 63;
    const int quad = ln >> 4;
    const int l15  = ln & 15;
    const floatx4 zz = (floatx4){0.f,0.f,0.f,0.f};

    // ---- stage xa: LN2 of 18x18 halo ----
    if (tid < 336){
        int hp = tid;
        int hy = hp / 18, hx = hp - hy*18;
        int gy = ty*16 + hy - 1, gx = tx*16 + hx - 1;
        bool ok = (hp < 324) && ((unsigned)gy < 128u) && ((unsigned)gx < 128u);
        if (ok){
            const float* xr = x_res + (((size_t)b << 14) + (gy << 7) + gx)*Cc;
            float v[Cc];
            const float4* x4 = reinterpret_cast<const float4*>(xr);
            float4* v4 = reinterpret_cast<float4*>(v);
            #pragma unroll
            for (int i = 0; i < Cc/4; i++) v4[i] = x4[i];
            float mean = 0.f;
            #pragma unroll
            for (int c = 0; c < Cc; c++) mean += v[c];
            mean *= (1.0f/Cc);
            float var = 0.f;
            #pragma unroll
            for (int c = 0; c < Cc; c++){ float d = v[c] - mean; var = fmaf(d, d, var); }
            var *= (1.0f/Cc);
            const float rinv = rsqrtf(var + 1e-5f);
            #pragma unroll
            for (int i = 0; i < 4; i++){
                float w0 = (v[8*i+0]-mean)*rinv*n2g[8*i+0] + n2b[8*i+0];
                float w1 = (v[8*i+1]-mean)*rinv*n2g[8*i+1] + n2b[8*i+1];
                float w2 = (v[8*i+2]-mean)*rinv*n2g[8*i+2] + n2b[8*i+2];
                float w3 = (v[8*i+3]-mean)*rinv*n2g[8*i+3] + n2b[8*i+3];
                float w4 = (v[8*i+4]-mean)*rinv*n2g[8*i+4] + n2b[8*i+4];
                float w5 = (v[8*i+5]-mean)*rinv*n2g[8*i+5] + n2b[8*i+5];
                float w6 = (v[8*i+6]-mean)*rinv*n2g[8*i+6] + n2b[8*i+6];
                float w7 = (v[8*i+7]-mean)*rinv*n2g[8*i+7] + n2b[8*i+7];
                uint4 dw;
                dw.x = pk2(w0,w1); dw.y = pk2(w2,w3);
                dw.z = pk2(w4,w5); dw.w = pk2(w6,w7);
                *(uint4*)(xa + hp*40 + i*8) = dw;
            }
        } else {
            uint4 z = {0,0,0,0};
            #pragma unroll
            for (int i = 0; i < 4; i++) *(uint4*)(xa + hp*40 + i*8) = z;
        }
    }

    // prefetch group 0 weights (3 slices) into regs
    uint4 pf0 = ((const uint4*)conv_wT)[tid];
    uint4 pf1 = ((const uint4*)conv_wT)[512  + tid];
    uint4 pf2 = ((const uint4*)conv_wT)[1024 + tid];

    floatx4 acc[2][8];
    #pragma unroll
    for (int j = 0; j < 2; j++)
        #pragma unroll
        for (int m = 0; m < 8; m++) acc[j][m] = zz;

    for (int g = 0; g < 12; g++){
        const int gm3 = g - (g/3)*3;       // g % 3 == ky of this group
        __syncthreads();   // wbuf readers (prev group) + y1c readers (prev kc) done

        if (gm3 == 0){
            // ---- lp1 chunk kc = g/3 ----
            const int kc = g / 3;
            short8 A1[2]; float4 b1[2];
            #pragma unroll
            for (int mt = 0; mt < 2; mt++){
                A1[mt] = *(const short8*)(lp1_wT + (kc*32 + mt*16 + l15)*32 + quad*8);
                b1[mt] = *(const float4*)(lp1_b + kc*32 + mt*16 + quad*4);
            }
            #pragma unroll
            for (int ii = 0; ii < 3; ii++){
                int nt = wv + 8*ii;
                if (nt < 21){
                    int px = nt*16 + l15;
                    int hy = px / 18, hx = px - hy*18;
                    int gy = ty*16 + hy - 1, gx = tx*16 + hx - 1;
                    bool oob = (px >= 324) || ((unsigned)gy > 127u) || ((unsigned)gx > 127u);
                    short8 Bx = *(const short8*)(xa + px*40 + quad*8);
                    #pragma unroll
                    for (int mt = 0; mt < 2; mt++){
                        floatx4 c = __builtin_amdgcn_mfma_f32_16x16x32_bf16(A1[mt], Bx, zz, 0,0,0);
                        float v0 = oob ? 0.f : gelu_f(c[0] + b1[mt].x);
                        float v1 = oob ? 0.f : gelu_f(c[1] + b1[mt].y);
                        float v2 = oob ? 0.f : gelu_f(c[2] + b1[mt].z);
                        float v3 = oob ? 0.f : gelu_f(c[3] + b1[mt].w);
                        uint2 pv; pv.x = pk2(v0, v1); pv.y = pk2(v2, v3);
                        *(uint2*)(y1c + px*40 + mt*16 + quad*4) = pv;
                    }
                }
            }
        }

        // stage this group's 3 weight slices from regs
        ((uint4*)wbuf)[tid]        = pf0;
        ((uint4*)wbuf)[512  + tid] = pf1;
        ((uint4*)wbuf)[1024 + tid] = pf2;
        __syncthreads();   // wbuf + y1c(kc) visible

        // prefetch next group (latency hidden under 48 MFMAs below)
        if (g < 11){
            pf0 = ((const uint4*)conv_wT)[(g+1)*1536 +        tid];
            pf1 = ((const uint4*)conv_wT)[(g+1)*1536 + 512  + tid];
            pf2 = ((const uint4*)conv_wT)[(g+1)*1536 + 1024 + tid];
        }

        const int ky = gm3;
        #pragma unroll
        for (int t = 0; t < 3; t++){       // kx = t
            const short* wb = wbuf + t*4096;
            short8 Bf[2];
            #pragma unroll
            for (int j = 0; j < 2; j++){
                int oy = wv*2 + j;
                int hp = (oy + ky)*18 + t + l15;
                Bf[j] = *(const short8*)(y1c + hp*40 + quad*8);
            }
            #pragma unroll
            for (int m = 0; m < 8; m++){
                short8 Aw = *(const short8*)(wb + quad*1024 + (m*16 + l15)*8);
                acc[0][m] = __builtin_amdgcn_mfma_f32_16x16x32_bf16(Aw, Bf[0], acc[0][m], 0,0,0);
                acc[1][m] = __builtin_amdgcn_mfma_f32_16x16x32_bf16(Aw, Bf[1], acc[1][m], 0,0,0);
            }
        }
    }

    __syncthreads();   // all conv/wbuf reads done -> overlay y2

    // ---- gelu(conv + bias) -> y2[px][co] bf16 ----
    #pragma unroll
    for (int j = 0; j < 2; j++){
        int px = (wv*2 + j)*16 + l15;
        #pragma unroll
        for (int m = 0; m < 8; m++){
            float4 cb = *(const float4*)(conv_b + m*16 + quad*4);
            floatx4 a = acc[j][m];
            float v0 = gelu_f(a[0] + cb.x);
            float v1 = gelu_f(a[1] + cb.y);
            float v2 = gelu_f(a[2] + cb.z);
            float v3 = gelu_f(a[3] + cb.w);
            uint2 pv; pv.x = pk2(v0, v1); pv.y = pk2(v2, v3);
            *(uint2*)(y2 + px*136 + m*16 + quad*4) = pv;
        }
    }
    __syncthreads();

    // ---- lp2 + gelu + residual ----
    short8 A2[2][4]; float4 lb[2];
    #pragma unroll
    for (int mt = 0; mt < 2; mt++){
        #pragma unroll
        for (int k = 0; k < 4; k++)
            A2[mt][k] = *(const short8*)(lp2_wT + (mt*16 + l15)*128 + k*32 + quad*8);
        lb[mt] = *(const float4*)(lp2_b + mt*16 + quad*4);
    }
    #pragma unroll
    for (int j = 0; j < 2; j++){
        int oy = wv*2 + j;
        floatx4 c2[2] = {zz, zz};
        #pragma unroll
        for (int k = 0; k < 4; k++){
            short8 Bf = *(const short8*)(y2 + (oy*16 + l15)*136 + k*32 + quad*8);
            c2[0] = __builtin_amdgcn_mfma_f32_16x16x32_bf16(A2[0][k], Bf, c2[0], 0,0,0);
            c2[1] = __builtin_amdgcn_mfma_f32_16x16x32_bf16(A2[1][k], Bf, c2[1], 0,0,0);
        }
        int gy = ty*16 + oy, gx = tx*16 + l15;
        size_t base = (((size_t)b << 14) + (gy << 7) + gx)*Cc;
        #pragma unroll
        for (int mt = 0; mt < 2; mt++){
            size_t ad = base + mt*16 + quad*4;
            float4 xr = *(const float4*)(x_res + ad);
            float4 ov;
            ov.x = gelu_f(c2[mt][0] + lb[mt].x) + xr.x;
            ov.y = gelu_f(c2[mt][1] + lb[mt].y) + xr.y;
            ov.z = gelu_f(c2[mt][2] + lb[mt].z) + xr.z;
            ov.w = gelu_f(c2[mt][3] + lb[mt].w) + xr.w;
            *(float4*)(out + ad) = ov;
        }
    }
}

extern "C" void kernel_launch(void* const* d_in, const int* in_sizes, int n_in,
                              void* d_out, int out_size, void* d_ws, size_t ws_size,
                              hipStream_t stream)
{
    (void)in_sizes; (void)n_in; (void)out_size; (void)ws_size;
    const float* x      = (const float*)d_in[0];
    const float* n1g    = (const float*)d_in[1];
    const float* n1b    = (const float*)d_in[2];
    const float* mod_w  = (const float*)d_in[3];
    const float* qkv_w  = (const float*)d_in[4];
    const float* qkv_b  = (const float*)d_in[5];
    const float* rpbt   = (const float*)d_in[6];
    const float* rev_w  = (const float*)d_in[7];
    const float* rev_b  = (const float*)d_in[8];
    const float* n2g    = (const float*)d_in[9];
    const float* n2b    = (const float*)d_in[10];
    const float* lp1_w  = (const float*)d_in[11];
    const float* lp1_b  = (const float*)d_in[12];
    const float* conv_w = (const float*)d_in[13];
    const float* conv_b = (const float*)d_in[14];
    const float* lp2_w  = (const float*)d_in[15];
    const float* lp2_b  = (const float*)d_in[16];
    float* out = (float*)d_out;

    char* wsb = (char*)d_ws;
    float*    x_res  = (float*)wsb;                       // 16 MB
    short*    qkv_wT = (short*)(wsb + 16777216);          // 49152 B
    short*    rev_wT = (short*)(wsb + 16826368);          // 16384 B (legacy)
    unsigned* rplbT  = (unsigned*)(wsb + 16842752);       // 30784 B
    short*    lp1_wT = (short*)(wsb + 16873536);          // 8192 B
    short*    conv_wT= (short*)(wsb + 16881728);          // 294912 B
    short*    lp2_wT = (short*)(wsb + 17176640);          // 8192 B
    short*    wvrT   = (short*)(wsb + 17184832);          // 16384 B
    float*    rbtot  = (float*)(wsb + 17201216);          // 128 B

    prep_kernel<<<799, 256, 0, stream>>>(qkv_w, rev_w, rpbt, lp1_w, conv_w, lp2_w,
                                         qkv_b, rev_b,
                                         qkv_wT, rev_wT, rplbT, lp1_wT, conv_wT, lp2_wT,
                                         wvrT, rbtot);
    attn_kernel<<<512, 512, 0, stream>>>(x, n1g, n1b, mod_w, qkv_b, rbtot,
                                         qkv_wT, wvrT, rplbT, x_res);
    leff_kernel<<<512, 512, 0, stream>>>(x_res, n2g, n2b, lp1_b, conv_b, lp2_b,
                                         lp1_wT, conv_wT, lp2_wT, out);
}

// Round 11
// 247.309 us; speedup vs baseline: 1.1681x; 1.1681x over previous
//
#include <hip/hip_runtime.h>
#include <math.h>

#define Fdim 128
#define Pw   16
#define Hh   8
#define Cc   32
#define Bb   8

typedef short  short8  __attribute__((ext_vector_type(8)));
typedef float  floatx4 __attribute__((ext_vector_type(4)));

#define QSCL   0.2550348637f      /* (1/sqrt(32)) * log2(e) */
#define MASKC2 (-144.26950408889634f)  /* -100 * log2(e) */

__device__ __forceinline__ float gelu_f(float x){
    return 0.5f * x * (1.0f + erff(x * 0.70710678118654752f));
}
// pack two fp32 -> bf16x2 (round-half-up) in 3 VALU ops via v_perm_b32
__device__ __forceinline__ unsigned pk2(float a, float b){
    unsigned ua = __builtin_bit_cast(unsigned, a) + 0x8000u;
    unsigned ub = __builtin_bit_cast(unsigned, b) + 0x8000u;
    return __builtin_amdgcn_perm(ub, ua, 0x07060302);
}
// truncating pack (1 op) — used for P in [0,1]; <=1ulp bf16 error
__device__ __forceinline__ unsigned pk2t(float a, float b){
    return __builtin_amdgcn_perm(__builtin_bit_cast(unsigned, b),
                                 __builtin_bit_cast(unsigned, a), 0x07060302);
}
__device__ __forceinline__ short bf16s(float a){
    return (short)((__builtin_bit_cast(unsigned, a) + 0x8000u) >> 16);
}
__device__ __forceinline__ float hi2f(unsigned d){ return __builtin_bit_cast(float, d & 0xffff0000u); }
__device__ __forceinline__ float lo2f(unsigned d){ return __builtin_bit_cast(float, d << 16); }

// ---------------- prep: bf16 weight repacks + V*Wrev fusion ----------------
__global__ __launch_bounds__(256) void prep_kernel(
    const float* __restrict__ qkv_w, const float* __restrict__ rev_w,
    const float* __restrict__ rpbt,  const float* __restrict__ lp1_w,
    const float* __restrict__ conv_w, const float* __restrict__ lp2_w,
    const float* __restrict__ qkv_b, const float* __restrict__ rev_b,
    short* __restrict__ qkv_wT, short* __restrict__ rev_wT, unsigned* __restrict__ rplb,
    short* __restrict__ lp1_wT, short* __restrict__ conv_wT, short* __restrict__ lp2_wT,
    short* __restrict__ wvr, float* __restrict__ rbtot)
{
    int i = blockIdx.x * 256 + threadIdx.x;
    if (i < 24576){
        int col = i >> 5, c = i & 31;
        qkv_wT[i] = bf16s(qkv_w[c*768 + col]);
    } else if (i < 32768){
        int j = i - 24576;
        int h = j >> 10, r = j & 1023;
        int c = r >> 5, a = r & 31;
        rev_wT[j] = bf16s(rev_w[(h*32 + a)*32 + c]);
    } else if (i < 40464){
        int j = i - 32768;
        int h = j / 962, d = j % 962;
        int g0 = (d < 481) ? (2*d) : (2*(d-481) + 1);
        float f0 = (g0     < 961) ? rpbt[g0*8 + h]*1.4426950408889634f : 0.f;
        float f1 = (g0 + 1 < 961) ? rpbt[(g0+1)*8 + h]*1.4426950408889634f : 0.f;
        rplb[j] = pk2(f0, f1);
    } else if (i < 44560){
        int j = i - 40464;
        int f = j >> 5, c = j & 31;
        lp1_wT[j] = bf16s(lp1_w[c*128 + f]);
    } else if (i < 192016){
        int j = i - 44560;                 // [kc][tap][kchunk][co][8]
        int ci_in = j & 7;
        int co    = (j >> 3) & 127;
        int chk   = (j >> 10) & 3;
        int s     = j >> 12;               // 0..35
        int tap = s % 9, kc = s / 9;
        conv_wT[j] = bf16s(conv_w[(tap*128 + kc*32 + chk*8 + ci_in)*128 + co]);
    } else if (i < 196112){
        int j = i - 192016;
        int oc = j >> 7, co = j & 127;
        lp2_wT[j] = bf16s(lp2_w[co*32 + oc]);
    } else if (i < 204304){
        // iteration order [h][c][aa]: rev_w reads coalesced across lanes,
        // qkv_w reads wave-broadcast (was c-lane-fast: 32 cachelines/iter gather)
        int j  = i - 196112;
        int h  = j >> 10, c = (j >> 5) & 31, aa = j & 31;
        float s = 0.f;
        #pragma unroll 4
        for (int a = 0; a < 32; a++)
            s += qkv_w[c*768 + 512 + h*32 + a] * rev_w[(h*32 + a)*32 + aa];
        wvr[h*1024 + aa*32 + c] = bf16s(s);   // output layout [h][cout][c] unchanged
    } else if (i < 204336){
        int aa = i - 204304;
        float s = rev_b[aa];
        for (int m = 0; m < 256; m++)
            s += qkv_b[512 + m] * rev_w[m*32 + aa];
        rbtot[aa] = s;
    }
}

// ---------------- MFMA shifted-window attention, 512 threads (8 waves) ----------------
__global__
__attribute__((amdgpu_flat_work_group_size(512,512), amdgpu_waves_per_eu(4,4)))
void attn_kernel(
    const float* __restrict__ x,   const float* __restrict__ n1g,
    const float* __restrict__ n1b, const float* __restrict__ mod_w,
    const float* __restrict__ qkv_b, const float* __restrict__ rbtot,
    const short* __restrict__ qkv_wT, const short* __restrict__ wvr,
    const unsigned* __restrict__ rplb,
    float* __restrict__ x_res)
{
    __shared__ __align__(16) short hmodS[4*256*8];  // [kchunk][tok][8]
    __shared__ __align__(16) short Kbuf[256*40];    // [tok][a]
    __shared__ __align__(16) short Qbuf[256*40];    // [tok][a] -> PT
    __shared__ __align__(16) short VTb[32*264];     // [c][tok]  (V~ = V@Wrev)
    __shared__ __align__(16) unsigned rplbS[962];
    __shared__ unsigned regnp[64];

    const int w  = blockIdx.x;
    const int b  = w >> 6;
    const int wi = w & 63;
    const int wh = wi >> 3, ww = wi & 7;
    const int tid  = threadIdx.x;
    const int wv   = tid >> 6;    // 0..7
    const int ln   = tid & 63;
    const int quad = ln >> 4;
    const int l15  = ln & 15;
    const bool masked = (wh == 7) || (ww == 7);

    // ---- stage: LN1 + mod_w -> hmodS bf16 (chunked layout); region table ----
    if (tid < 256){
        const int n  = tid;
        const int rn = n >> 4, cn = n & 15;
        const int gh = (wh*Pw + rn + 8) & 127;
        const int gw = (ww*Pw + cn + 8) & 127;
        const float* xr = x + (((size_t)b << 14) + (gh << 7) + gw) * Cc;
        float v[Cc];
        const float4* x4 = reinterpret_cast<const float4*>(xr);
        float4* v4 = reinterpret_cast<float4*>(v);
        #pragma unroll
        for (int i = 0; i < Cc/4; i++) v4[i] = x4[i];
        float mean = 0.f;
        #pragma unroll
        for (int c = 0; c < Cc; c++) mean += v[c];
        mean *= (1.0f/Cc);
        float var = 0.f;
        #pragma unroll
        for (int c = 0; c < Cc; c++){ float d = v[c] - mean; var = fmaf(d, d, var); }
        var *= (1.0f/Cc);
        const float rinv = rsqrtf(var + 1e-5f);
        #pragma unroll
        for (int c = 0; c < Cc; c++)
            v[c] = (v[c] - mean)*rinv*n1g[c] + n1b[c] + mod_w[n*Cc + c];
        #pragma unroll
        for (int i = 0; i < 4; i++){
            uint4 dw;
            dw.x = pk2(v[8*i+0], v[8*i+1]);
            dw.y = pk2(v[8*i+2], v[8*i+3]);
            dw.z = pk2(v[8*i+4], v[8*i+5]);
            dw.w = pk2(v[8*i+6], v[8*i+7]);
            *(uint4*)(&hmodS[i*2048 + n*8]) = dw;
        }
    }
    if (tid < 64){
        int rm  = tid >> 2;
        int shm = wh*Pw + rm;
        int hreg = (shm < 112) ? 0 : ((shm < 120) ? 1 : 2);
        unsigned dw = 0;
        #pragma unroll
        for (int i = 0; i < 4; i++){
            int cm  = (tid & 3)*4 + i;
            int swm = ww*Pw + cm;
            int wreg = (swm < 112) ? 0 : ((swm < 120) ? 1 : 2);
            dw |= (unsigned)(hreg*3 + wreg) << (8*i);
        }
        regnp[tid] = dw;
    }
    __syncthreads();

    unsigned regq[2] = {0,0};
    if (masked){
        #pragma unroll
        for (int nt = 0; nt < 2; nt++){
            int q = wv*32 + nt*16 + l15;
            regq[nt] = (regnp[q >> 2] >> ((q & 3)*8)) & 255u;
        }
    }

    floatx4 RV[2][2];
    #pragma unroll
    for (int cm = 0; cm < 2; cm++)
        #pragma unroll
        for (int nt = 0; nt < 2; nt++)
            RV[cm][nt] = (floatx4){0.f,0.f,0.f,0.f};

    const int s0lane = 12 + l15 - 4*quad;
    const floatx4 zz = (floatx4){0.f,0.f,0.f,0.f};
    const short8 ONEv = {0x3F80,0x3F80,0x3F80,0x3F80,0x3F80,0x3F80,0x3F80,0x3F80};

    for (int h = 0; h < Hh; h++){
        __syncthreads();   // B1: prev head's Kbuf/VTb/rplbS reads done

        #pragma unroll
        for (int k2 = 0; k2 < 2; k2++){
            int i = k2*512 + tid;
            if (i < 962) rplbS[i] = rplb[h*962 + i];
        }

        // ---- QKV phase (V is the fused V@Wrev) ----
        short8 HF[2];
        #pragma unroll
        for (int ii = 0; ii < 2; ii++)
            HF[ii] = *(const short8*)(&hmodS[quad*2048 + (wv*32 + ii*16 + l15)*8]);
        short8 WQ[2], WK[2], WVb[2];
        float4 bq[2], bk[2];
        #pragma unroll
        for (int mt = 0; mt < 2; mt++){
            WQ[mt]  = *(const short8*)(qkv_wT + (      h*32 + mt*16 + l15)*32 + quad*8);
            WK[mt]  = *(const short8*)(qkv_wT + (256 + h*32 + mt*16 + l15)*32 + quad*8);
            WVb[mt] = *(const short8*)(wvr    + (      h*32 + mt*16 + l15)*32 + quad*8);
            bq[mt]  = *(const float4*)(qkv_b +       h*32 + mt*16 + quad*4);
            bk[mt]  = *(const float4*)(qkv_b + 256 + h*32 + mt*16 + quad*4);
        }
        #pragma unroll
        for (int ii = 0; ii < 2; ii++){
            const int tok = wv*32 + ii*16;
            #pragma unroll
            for (int mt = 0; mt < 2; mt++){
                floatx4 qf = __builtin_amdgcn_mfma_f32_16x16x32_bf16(WQ[mt], HF[ii], zz, 0,0,0);
                floatx4 kf = __builtin_amdgcn_mfma_f32_16x16x32_bf16(WK[mt], HF[ii], zz, 0,0,0);
                floatx4 vf = __builtin_amdgcn_mfma_f32_16x16x32_bf16(HF[ii], WVb[mt], zz, 0,0,0);
                uint2 qv;
                qv.x = pk2((qf[0]+bq[mt].x)*QSCL, (qf[1]+bq[mt].y)*QSCL);
                qv.y = pk2((qf[2]+bq[mt].z)*QSCL, (qf[3]+bq[mt].w)*QSCL);
                *(uint2*)(&Qbuf[(tok + l15)*40 + mt*16 + quad*4]) = qv;
                uint2 kv;
                kv.x = pk2(kf[0]+bk[mt].x, kf[1]+bk[mt].y);
                kv.y = pk2(kf[2]+bk[mt].z, kf[3]+bk[mt].w);
                *(uint2*)(&Kbuf[(tok + l15)*40 + mt*16 + quad*4]) = kv;
                uint2 vv;
                vv.x = pk2(vf[0], vf[1]);
                vv.y = pk2(vf[2], vf[3]);
                *(uint2*)(&VTb[(mt*16 + l15)*264 + tok + quad*4]) = vv;
            }
        }
        __syncthreads();   // B2

        short8 QB[2];
        #pragma unroll
        for (int nt = 0; nt < 2; nt++)
            QB[nt] = *(const short8*)(&Qbuf[(wv*32 + nt*16 + l15)*40 + quad*8]);

        floatx4 OT[2][2];
        #pragma unroll
        for (int am = 0; am < 2; am++)
            #pragma unroll
            for (int nt = 0; nt < 2; nt++)
                OT[am][nt] = (floatx4){0.f,0.f,0.f,0.f};
        floatx4 RS[2] = {zz, zz};   // rowsum via ones-MFMA

        for (int ch = 0; ch < 8; ch++){
            short8 KA[2];
            KA[0] = *(const short8*)(&Kbuf[(ch*32 +      l15)*40 + quad*8]);
            KA[1] = *(const short8*)(&Kbuf[(ch*32 + 16 + l15)*40 + quad*8]);

            unsigned pd0[3], pd1[3];
            int base = wv*2 - ch*2;
            #pragma unroll
            for (int j = 0; j < 3; j++){
                int dt  = base + j - 1;
                int g0  = (dt + 15)*31 + s0lane;
                int dwi = (g0 & 1) ? (481 + (g0 >> 1)) : (g0 >> 1);
                pd0[j] = rplbS[dwi];
                pd1[j] = rplbS[dwi + 1];
            }
            unsigned rk[2] = {0,0};
            if (masked){
                rk[0] = regnp[ch*8 +     quad];
                rk[1] = regnp[ch*8 + 4 + quad];
            }

            #pragma unroll
            for (int sub = 0; sub < 2; sub++){
                #pragma unroll
                for (int nt = 0; nt < 2; nt++){
                    int j = nt - sub + 1;
                    floatx4 ci;
                    ci[0] = hi2f(pd1[j]); ci[1] = lo2f(pd1[j]);
                    ci[2] = hi2f(pd0[j]); ci[3] = lo2f(pd0[j]);
                    if (masked){
                        ci[0] += (((rk[sub]      ) & 255u) == regq[nt]) ? 0.f : MASKC2;
                        ci[1] += (((rk[sub] >>  8) & 255u) == regq[nt]) ? 0.f : MASKC2;
                        ci[2] += (((rk[sub] >> 16) & 255u) == regq[nt]) ? 0.f : MASKC2;
                        ci[3] += (((rk[sub] >> 24) & 255u) == regq[nt]) ? 0.f : MASKC2;
                    }
                    floatx4 S = __builtin_amdgcn_mfma_f32_16x16x32_bf16(KA[sub], QB[nt], ci, 0,0,0);
                    float p0 = __builtin_amdgcn_exp2f(S[0]);
                    float p1 = __builtin_amdgcn_exp2f(S[1]);
                    float p2 = __builtin_amdgcn_exp2f(S[2]);
                    float p3 = __builtin_amdgcn_exp2f(S[3]);
                    uint2 pv; pv.x = pk2t(p0, p1); pv.y = pk2t(p2, p3);
                    *(uint2*)(&Qbuf[(wv*32 + nt*16 + l15)*40 + sub*16 + quad*4]) = pv;
                }
            }

            short8 VA0 = *(const short8*)(&VTb[(     l15)*264 + ch*32 + quad*8]);
            short8 VA1 = *(const short8*)(&VTb[(16 + l15)*264 + ch*32 + quad*8]);
            #pragma unroll
            for (int nt = 0; nt < 2; nt++){
                short8 PB = *(const short8*)(&Qbuf[(wv*32 + nt*16 + l15)*40 + quad*8]);
                OT[0][nt] = __builtin_amdgcn_mfma_f32_16x16x32_bf16(VA0, PB, OT[0][nt], 0,0,0);
                OT[1][nt] = __builtin_amdgcn_mfma_f32_16x16x32_bf16(VA1, PB, OT[1][nt], 0,0,0);
                RS[nt]    = __builtin_amdgcn_mfma_f32_16x16x32_bf16(ONEv, PB, RS[nt], 0,0,0);
            }
        }

        // accumulate this head: RV += OT / rowsum  (fp32, no LDS roundtrip)
        float inv[2];
        inv[0] = 1.0f / RS[0][0];
        inv[1] = 1.0f / RS[1][0];
        #pragma unroll
        for (int am = 0; am < 2; am++)
            #pragma unroll
            for (int nt = 0; nt < 2; nt++){
                floatx4 o = OT[am][nt];
                float iv = inv[nt];
                RV[am][nt][0] = fmaf(o[0], iv, RV[am][nt][0]);
                RV[am][nt][1] = fmaf(o[1], iv, RV[am][nt][1]);
                RV[am][nt][2] = fmaf(o[2], iv, RV[am][nt][2]);
                RV[am][nt][3] = fmaf(o[3], iv, RV[am][nt][3]);
            }
    }

    // ---- epilogue: x_res = x + rbtot + attn_out ----
    #pragma unroll
    for (int cm = 0; cm < 2; cm++){
        float4 rb = *(const float4*)(rbtot + cm*16 + quad*4);
        #pragma unroll
        for (int nt = 0; nt < 2; nt++){
            int gh = (wh*Pw + wv*2 + nt + 8) & 127;
            int gw = (ww*Pw + l15 + 8) & 127;
            size_t gaddr = (((size_t)b << 14) + (gh << 7) + gw)*Cc + cm*16 + quad*4;
            float4 xv = *(const float4*)(x + gaddr);
            floatx4 o = RV[cm][nt];
            float4 ov;
            ov.x = xv.x + rb.x + o[0];
            ov.y = xv.y + rb.y + o[1];
            ov.z = xv.z + rb.z + o[2];
            ov.w = xv.w + rb.w + o[3];
            *(float4*)(x_res + gaddr) = ov;
        }
    }
}

// ---------------- LeFF via MFMA, 512 threads (8 waves) — known-good wbuf ping-pong ----------------
__global__
__attribute__((amdgpu_flat_work_group_size(512,512), amdgpu_waves_per_eu(4,4)))
void leff_kernel(
    const float* __restrict__ x_res, const float* __restrict__ n2g,
    const float* __restrict__ n2b,  const float* __restrict__ lp1_b,
    const float* __restrict__ conv_b, const float* __restrict__ lp2_b,
    const short* __restrict__ lp1_wT, const short* __restrict__ conv_wT,
    const short* __restrict__ lp2_wT, float* __restrict__ out)
{
    __shared__ __align__(16) char lds[70144];
    short* xa   = (short*)lds;             // [336][40] bf16 LN2(halo)
    short* y1c  = (short*)(lds + 26880);   // [336][40] bf16 y1 chunk
    short* wbuf = (short*)(lds + 53760);   // [2][kchunk4][co128][8] ping-pong
    short* y2   = (short*)lds;             // [256][136] overlay after conv

    const int blk = blockIdx.x;
    const int b   = blk >> 6;
    const int ty  = (blk >> 3) & 7, tx = blk & 7;
    const int tid  = threadIdx.x;
    const int wv   = tid >> 6;    // 0..7
    const int ln   = tid & 63;
    const int quad = ln >> 4;
    const int l15  = ln & 15;
    const floatx4 zz = (floatx4){0.f,0.f,0.f,0.f};

    // ---- stage xa: LN2 of 18x18 halo ----
    if (tid < 336){
        int hp = tid;
        int hy = hp / 18, hx = hp - hy*18;
        int gy = ty*16 + hy - 1, gx = tx*16 + hx - 1;
        bool ok = (hp < 324) && ((unsigned)gy < 128u) && ((unsigned)gx < 128u);
        if (ok){
            const float* xr = x_res + (((size_t)b << 14) + (gy << 7) + gx)*Cc;
            float v[Cc];
            const float4* x4 = reinterpret_cast<const float4*>(xr);
            float4* v4 = reinterpret_cast<float4*>(v);
            #pragma unroll
            for (int i = 0; i < Cc/4; i++) v4[i] = x4[i];
            float mean = 0.f;
            #pragma unroll
            for (int c = 0; c < Cc; c++) mean += v[c];
            mean *= (1.0f/Cc);
            float var = 0.f;
            #pragma unroll
            for (int c = 0; c < Cc; c++){ float d = v[c] - mean; var = fmaf(d, d, var); }
            var *= (1.0f/Cc);
            const float rinv = rsqrtf(var + 1e-5f);
            #pragma unroll
            for (int i = 0; i < 4; i++){
                float w0 = (v[8*i+0]-mean)*rinv*n2g[8*i+0] + n2b[8*i+0];
                float w1 = (v[8*i+1]-mean)*rinv*n2g[8*i+1] + n2b[8*i+1];
                float w2 = (v[8*i+2]-mean)*rinv*n2g[8*i+2] + n2b[8*i+2];
                float w3 = (v[8*i+3]-mean)*rinv*n2g[8*i+3] + n2b[8*i+3];
                float w4 = (v[8*i+4]-mean)*rinv*n2g[8*i+4] + n2b[8*i+4];
                float w5 = (v[8*i+5]-mean)*rinv*n2g[8*i+5] + n2b[8*i+5];
                float w6 = (v[8*i+6]-mean)*rinv*n2g[8*i+6] + n2b[8*i+6];
                float w7 = (v[8*i+7]-mean)*rinv*n2g[8*i+7] + n2b[8*i+7];
                uint4 dw;
                dw.x = pk2(w0,w1); dw.y = pk2(w2,w3);
                dw.z = pk2(w4,w5); dw.w = pk2(w6,w7);
                *(uint4*)(xa + hp*40 + i*8) = dw;
            }
        } else {
            uint4 z = {0,0,0,0};
            #pragma unroll
            for (int i = 0; i < 4; i++) *(uint4*)(xa + hp*40 + i*8) = z;
        }
    }

    // stage weight slice 0 (pure linear copy: layout matches LDS)
    ((uint4*)wbuf)[tid] = ((const uint4*)conv_wT)[tid];

    floatx4 acc[2][8];
    #pragma unroll
    for (int j = 0; j < 2; j++)
        #pragma unroll
        for (int m = 0; m < 8; m++) acc[j][m] = zz;

    for (int idx = 0; idx < 36; idx++){
        const int kc  = idx / 9;
        const int tap = idx - kc*9;

        if (tap == 0){
            __syncthreads();   // prior conv reads of y1c done
            short8 A1[2]; float4 b1[2];
            #pragma unroll
            for (int mt = 0; mt < 2; mt++){
                A1[mt] = *(const short8*)(lp1_wT + (kc*32 + mt*16 + l15)*32 + quad*8);
                b1[mt] = *(const float4*)(lp1_b + kc*32 + mt*16 + quad*4);
            }
            #pragma unroll
            for (int ii = 0; ii < 3; ii++){
                int nt = wv + 8*ii;
                if (nt < 21){
                    int px = nt*16 + l15;
                    int hy = px / 18, hx = px - hy*18;
                    int gy = ty*16 + hy - 1, gx = tx*16 + hx - 1;
                    bool oob = (px >= 324) || ((unsigned)gy > 127u) || ((unsigned)gx > 127u);
                    short8 Bx = *(const short8*)(xa + px*40 + quad*8);
                    #pragma unroll
                    for (int mt = 0; mt < 2; mt++){
                        floatx4 c = __builtin_amdgcn_mfma_f32_16x16x32_bf16(A1[mt], Bx, zz, 0,0,0);
                        float v0 = oob ? 0.f : gelu_f(c[0] + b1[mt].x);
                        float v1 = oob ? 0.f : gelu_f(c[1] + b1[mt].y);
                        float v2 = oob ? 0.f : gelu_f(c[2] + b1[mt].z);
                        float v3 = oob ? 0.f : gelu_f(c[3] + b1[mt].w);
                        uint2 pv; pv.x = pk2(v0, v1); pv.y = pk2(v2, v3);
                        *(uint2*)(y1c + px*40 + mt*16 + quad*4) = pv;
                    }
                }
            }
        }

        uint4 pf;
        if (idx < 35) pf = ((const uint4*)conv_wT)[(idx + 1)*512 + tid];

        __syncthreads();   // wbuf[idx&1] + y1c(kc) visible

        const short* wb = wbuf + (idx & 1)*4096;
        const int ky = tap / 3, kx = tap - ky*3;

        short8 Bf[2];
        #pragma unroll
        for (int j = 0; j < 2; j++){
            int oy = wv*2 + j;
            int hp = (oy + ky)*18 + kx + l15;
            Bf[j] = *(const short8*)(y1c + hp*40 + quad*8);
        }
        #pragma unroll
        for (int m = 0; m < 8; m++){
            short8 Aw = *(const short8*)(wb + quad*1024 + (m*16 + l15)*8);
            acc[0][m] = __builtin_amdgcn_mfma_f32_16x16x32_bf16(Aw, Bf[0], acc[0][m], 0,0,0);
            acc[1][m] = __builtin_amdgcn_mfma_f32_16x16x32_bf16(Aw, Bf[1], acc[1][m], 0,0,0);
        }

        if (idx < 35)
            ((uint4*)(wbuf + ((idx + 1) & 1)*4096))[tid] = pf;
    }

    __syncthreads();   // all conv/wbuf reads done -> overlay y2

    // ---- gelu(conv + bias) -> y2[px][co] bf16 ----
    #pragma unroll
    for (int j = 0; j < 2; j++){
        int px = (wv*2 + j)*16 + l15;
        #pragma unroll
        for (int m = 0; m < 8; m++){
            float4 cb = *(const float4*)(conv_b + m*16 + quad*4);
            floatx4 a = acc[j][m];
            float v0 = gelu_f(a[0] + cb.x);
            float v1 = gelu_f(a[1] + cb.y);
            float v2 = gelu_f(a[2] + cb.z);
            float v3 = gelu_f(a[3] + cb.w);
            uint2 pv; pv.x = pk2(v0, v1); pv.y = pk2(v2, v3);
            *(uint2*)(y2 + px*136 + m*16 + quad*4) = pv;
        }
    }
    __syncthreads();

    // ---- lp2 + gelu + residual ----
    short8 A2[2][4]; float4 lb[2];
    #pragma unroll
    for (int mt = 0; mt < 2; mt++){
        #pragma unroll
        for (int k = 0; k < 4; k++)
            A2[mt][k] = *(const short8*)(lp2_wT + (mt*16 + l15)*128 + k*32 + quad*8);
        lb[mt] = *(const float4*)(lp2_b + mt*16 + quad*4);
    }
    #pragma unroll
    for (int j = 0; j < 2; j++){
        int oy = wv*2 + j;
        floatx4 c2[2] = {zz, zz};
        #pragma unroll
        for (int k = 0; k < 4; k++){
            short8 Bf = *(const short8*)(y2 + (oy*16 + l15)*136 + k*32 + quad*8);
            c2[0] = __builtin_amdgcn_mfma_f32_16x16x32_bf16(A2[0][k], Bf, c2[0], 0,0,0);
            c2[1] = __builtin_amdgcn_mfma_f32_16x16x32_bf16(A2[1][k], Bf, c2[1], 0,0,0);
        }
        int gy = ty*16 + oy, gx = tx*16 + l15;
        size_t base = (((size_t)b << 14) + (gy << 7) + gx)*Cc;
        #pragma unroll
        for (int mt = 0; mt < 2; mt++){
            size_t ad = base + mt*16 + quad*4;
            float4 xr = *(const float4*)(x_res + ad);
            float4 ov;
            ov.x = gelu_f(c2[mt][0] + lb[mt].x) + xr.x;
            ov.y = gelu_f(c2[mt][1] + lb[mt].y) + xr.y;
            ov.z = gelu_f(c2[mt][2] + lb[mt].z) + xr.z;
            ov.w = gelu_f(c2[mt][3] + lb[mt].w) + xr.w;
            *(float4*)(out + ad) = ov;
        }
    }
}

extern "C" void kernel_launch(void* const* d_in, const int* in_sizes, int n_in,
                              void* d_out, int out_size, void* d_ws, size_t ws_size,
                              hipStream_t stream)
{
    (void)in_sizes; (void)n_in; (void)out_size; (void)ws_size;
    const float* x      = (const float*)d_in[0];
    const float* n1g    = (const float*)d_in[1];
    const float* n1b    = (const float*)d_in[2];
    const float* mod_w  = (const float*)d_in[3];
    const float* qkv_w  = (const float*)d_in[4];
    const float* qkv_b  = (const float*)d_in[5];
    const float* rpbt   = (const float*)d_in[6];
    const float* rev_w  = (const float*)d_in[7];
    const float* rev_b  = (const float*)d_in[8];
    const float* n2g    = (const float*)d_in[9];
    const float* n2b    = (const float*)d_in[10];
    const float* lp1_w  = (const float*)d_in[11];
    const float* lp1_b  = (const float*)d_in[12];
    const float* conv_w = (const float*)d_in[13];
    const float* conv_b = (const float*)d_in[14];
    const float* lp2_w  = (const float*)d_in[15];
    const float* lp2_b  = (const float*)d_in[16];
    float* out = (float*)d_out;

    char* wsb = (char*)d_ws;
    float*    x_res  = (float*)wsb;                       // 16 MB
    short*    qkv_wT = (short*)(wsb + 16777216);          // 49152 B
    short*    rev_wT = (short*)(wsb + 16826368);          // 16384 B (legacy)
    unsigned* rplbT  = (unsigned*)(wsb + 16842752);       // 30784 B
    short*    lp1_wT = (short*)(wsb + 16873536);          // 8192 B
    short*    conv_wT= (short*)(wsb + 16881728);          // 294912 B
    short*    lp2_wT = (short*)(wsb + 17176640);          // 8192 B
    short*    wvrT   = (short*)(wsb + 17184832);          // 16384 B
    float*    rbtot  = (float*)(wsb + 17201216);          // 128 B

    prep_kernel<<<799, 256, 0, stream>>>(qkv_w, rev_w, rpbt, lp1_w, conv_w, lp2_w,
                                         qkv_b, rev_b,
                                         qkv_wT, rev_wT, rplbT, lp1_wT, conv_wT, lp2_wT,
                                         wvrT, rbtot);
    attn_kernel<<<512, 512, 0, stream>>>(x, n1g, n1b, mod_w, qkv_b, rbtot,
                                         qkv_wT, wvrT, rplbT, x_res);
    leff_kernel<<<512, 512, 0, stream>>>(x_res, n2g, n2b, lp1_b, conv_b, lp2_b,
                                         lp1_wT, conv_wT, lp2_wT, out);
}